// Round 7
// baseline (1160.112 us; speedup 1.0000x reference)
//
#include <hip/hip_runtime.h>

#define N_NODES 100000
#define NNZ_E   3200000
#define SLOPE   0.25f

// ---- bucket sort geometry ----
#define NBUCK 782      // ceil(100000/128); bucket = row >> 7 (128 rows/bucket)
#define PBLK  512      // partition blocks
#define PCH   6250     // edges per partition block (512*6250 = 3,200,000 exact)

typedef __attribute__((ext_vector_type(8))) short bf16x8;
typedef __attribute__((ext_vector_type(4))) float f32x4;

// f32 -> bf16 round-to-nearest-even (bit trick)
__device__ __forceinline__ unsigned short f2b(float f) {
    union { float f; unsigned int u; } c; c.f = f;
    unsigned int u = c.u + 0x7fffu + ((c.u >> 16) & 1u);
    return (unsigned short)(u >> 16);
}
__device__ __forceinline__ unsigned int pack2(float a, float b) {
    return (unsigned int)f2b(a) | ((unsigned int)f2b(b) << 16);
}
__device__ __forceinline__ float b2f_lo(unsigned int u) {
    union { unsigned int u; float f; } c; c.u = u << 16; return c.f;
}
__device__ __forceinline__ float b2f_hi(unsigned int u) {
    union { unsigned int u; float f; } c; c.u = u & 0xffff0000u; return c.f;
}

// async global->LDS, 16B per lane; LDS dest is wave-uniform base + lane*16
__device__ __forceinline__ void load_lds16(const unsigned short* gp, unsigned short* lp) {
    __builtin_amdgcn_global_load_lds(
        (const __attribute__((address_space(1))) void*)gp,
        (__attribute__((address_space(3))) void*)lp, 16, 0, 0);
}

// ---------------- CSR build: two-level counting sort ----------------
__global__ __launch_bounds__(256) void partition_kernel(
    const int* __restrict__ rows, const int* __restrict__ cols,
    const float* __restrict__ vals,
    int2* __restrict__ stagedP,
    int* __restrict__ offs /*[PBLK][NBUCK+1]*/, int* __restrict__ btot)
{
    __shared__ int hist[NBUCK];   // counts, then running cursors
    __shared__ int ts[256];
    const int blk = blockIdx.x, t = threadIdx.x;
    const int base = blk * PCH;

    for (int i = t; i < NBUCK; i += 256) hist[i] = 0;
    __syncthreads();
    for (int e = t; e < PCH; e += 256)
        atomicAdd(&hist[rows[base + e] >> 7], 1);
    __syncthreads();

    // exclusive scan over 782 buckets: 4 entries per thread + 256-thread scan
    const int i0 = t << 2;
    int c0 = (i0 + 0 < NBUCK) ? hist[i0 + 0] : 0;
    int c1 = (i0 + 1 < NBUCK) ? hist[i0 + 1] : 0;
    int c2 = (i0 + 2 < NBUCK) ? hist[i0 + 2] : 0;
    int c3 = (i0 + 3 < NBUCK) ? hist[i0 + 3] : 0;
    int s = c0 + c1 + c2 + c3;
    ts[t] = s; __syncthreads();
    for (int off = 1; off < 256; off <<= 1) {
        int u = (t >= off) ? ts[t - off] : 0;
        __syncthreads();
        ts[t] += u;
        __syncthreads();
    }
    int ex = ts[t] - s;
    int o0 = ex, o1 = ex + c0, o2 = o1 + c1, o3 = o2 + c2;
    int* gof = offs + blk * (NBUCK + 1);
    if (i0 + 0 < NBUCK) { hist[i0 + 0] = o0; gof[i0 + 0] = o0; if (c0) atomicAdd(&btot[i0 + 0], c0); }
    if (i0 + 1 < NBUCK) { hist[i0 + 1] = o1; gof[i0 + 1] = o1; if (c1) atomicAdd(&btot[i0 + 1], c1); }
    if (i0 + 2 < NBUCK) { hist[i0 + 2] = o2; gof[i0 + 2] = o2; if (c2) atomicAdd(&btot[i0 + 2], c2); }
    if (i0 + 3 < NBUCK) { hist[i0 + 3] = o3; gof[i0 + 3] = o3; if (c3) atomicAdd(&btot[i0 + 3], c3); }
    if (t == 255) gof[NBUCK] = ts[255];   // == PCH
    __syncthreads();

    // scatter into block-local staged region (random only within ~50 KB, L2-held)
    for (int e = t; e < PCH; e += 256) {
        int r = rows[base + e];
        int p = atomicAdd(&hist[r >> 7], 1);
        stagedP[base + p] = make_int2(((r & 127) << 17) | cols[base + e],
                                      __float_as_int(vals[base + e]));
    }
}

// Pass 1b: exclusive scan of bucket totals -> epack base per bucket
__global__ __launch_bounds__(1024) void bscan_kernel(const int* __restrict__ btot,
                                                     int* __restrict__ bbase,
                                                     int* __restrict__ roff) {
    __shared__ int lds[1024];
    int t = threadIdx.x;
    int v = (t < NBUCK) ? btot[t] : 0;
    lds[t] = v; __syncthreads();
    for (int off = 1; off < 1024; off <<= 1) {
        int u = (t >= off) ? lds[t - off] : 0;
        __syncthreads();
        lds[t] += u;
        __syncthreads();
    }
    if (t < NBUCK) bbase[t] = lds[t] - v;
    if (t == 0) { bbase[NBUCK] = NNZ_E; roff[N_NODES] = NNZ_E; }
}

// Pass 2: one block per bucket. Two direct passes over the bucket's 512 slices:
// count rows -> scan -> place via per-row cursors. LDS ~6 KB -> high occupancy.
__global__ __launch_bounds__(256) void place_kernel(
    const int* __restrict__ offs, const int* __restrict__ bbase,
    const int2* __restrict__ stagedP,
    int* __restrict__ roff, int2* __restrict__ epack)
{
    __shared__ int sstart[PBLK];
    __shared__ int slen[PBLK];
    __shared__ int cnt[128];
    __shared__ int rex[128];
    const int b = blockIdx.x, t = threadIdx.x;

    for (int i = t; i < PBLK; i += 256) {
        int s = offs[i * (NBUCK + 1) + b];
        int e = offs[i * (NBUCK + 1) + b + 1];
        sstart[i] = s;
        slen[i] = e - s;
    }
    if (t < 128) cnt[t] = 0;
    __syncthreads();

    // count pass: row histogram (read only .x of each staged edge)
    for (int i = t; i < PBLK; i += 256) {
        const int s0 = sstart[i], len = slen[i];
        const int* p = (const int*)(stagedP + (size_t)i * PCH + s0);
        for (int j = 0; j < len; ++j) {
            int rl = (p[2 * j] >> 17) & 127;
            atomicAdd(&cnt[rl], 1);
        }
    }
    __syncthreads();

    // exclusive scan of 128 row counts
    int cv = (t < 128) ? cnt[t] : 0;
    if (t < 128) rex[t] = cv;
    __syncthreads();
    for (int off = 1; off < 128; off <<= 1) {
        int u = (t >= off && t < 128) ? rex[t - off] : 0;
        __syncthreads();
        if (t < 128) rex[t] += u;
        __syncthreads();
    }
    const int bb = bbase[b];
    int exl = (t < 128) ? (rex[t] - cv) : 0;
    __syncthreads();
    if (t < 128) {
        rex[t] = exl;
        cnt[t] = 0;                   // becomes per-row cursor
        int idx = (b << 7) + t;
        if (idx < N_NODES) roff[idx] = bb + exl;
    }
    __syncthreads();

    // place pass
    for (int i = t; i < PBLK; i += 256) {
        const int s0 = sstart[i], len = slen[i];
        const int2* p = stagedP + (size_t)i * PCH + s0;
        for (int j = 0; j < len; ++j) {
            int2 ed = p[j];
            int rl = (ed.x >> 17) & 127;
            int pos = bb + rex[rl] + atomicAdd(&cnt[rl], 1);
            epack[pos] = make_int2(ed.x & 0x1FFFF, ed.y);
        }
    }
}

// ---------------- weight prep (all three layers in one launch) ----------------
__global__ __launch_bounds__(256) void wprep3_kernel(
    const float* __restrict__ W1, unsigned short* __restrict__ Wt1,
    const float* __restrict__ W2, unsigned short* __restrict__ Wt2,
    const float* __restrict__ W3, unsigned short* __restrict__ Wt3)
{
    int idx = blockIdx.x * blockDim.x + threadIdx.x;
    if (idx < 131072) {                    // W1: 512x256
        int n = idx >> 9, k = idx & 511;
        Wt1[idx] = f2b(W1[(size_t)k * 256 + n]);
    } else if (idx < 131072 + 65536) {     // W2: 256x256
        int i = idx - 131072;
        int n = i >> 8, k = i & 255;
        Wt2[i] = f2b(W2[(size_t)k * 256 + n]);
    } else if (idx < 131072 + 65536 + 32768) {  // W3: 256x128
        int i = idx - 131072 - 65536;
        int n = i >> 8, k = i & 255;
        Wt3[i] = f2b(W3[(size_t)k * 128 + n]);
    }
}

// ---------------- bf16 MFMA GEMM, 128x256 tile, SINGLE-buffered ----------------
// A staged once per k-step and reused by both 128-col halves (halves A traffic
// vs the 128x128 pair). 24 KB LDS, ~136 VGPR -> 3 blocks/CU (R3-proven shape).
// AF32=1: A is f32, converted to bf16 in-register during staging (fuses conv).
template<int AF32>
__global__ __launch_bounds__(256) void gemm256s(
    const void* __restrict__ Av,            // [M,K] f32 (AF32) or bf16
    const unsigned short* __restrict__ Bt,  // [256,K] bf16
    unsigned short* __restrict__ C,         // [M,256] bf16
    int M, int K)
{
    __shared__ __align__(16) unsigned short As[128 * 32];   // 8 KB
    __shared__ __align__(16) unsigned short Bs[256 * 32];   // 16 KB
    const int t = threadIdx.x;
    const int wave = t >> 6, lane = t & 63;
    const int wm = wave & 1, wn = wave >> 1;
    const int quad = lane >> 4, l16 = lane & 15;
    const int row0 = blockIdx.x * 128;

    f32x4 acc[4][8];
#pragma unroll
    for (int mt = 0; mt < 4; ++mt)
#pragma unroll
        for (int nt = 0; nt < 8; ++nt) acc[mt][nt] = (f32x4){0.f, 0.f, 0.f, 0.f};

    const int sr0 = wave * 16 + (lane >> 2);   // 0..63
    const int sc  = (lane & 3) << 3;

    // A f32-staging mapping: thread t handles row t>>1, cols half*16..+16
    const int arow = t >> 1, ahalf = t & 1;
    int araw = row0 + arow; if (araw > M - 1) araw = M - 1;
    const float* Af = (const float*)Av;
    const unsigned short* Ab = (const unsigned short*)Av;

    int ra0 = row0 + sr0;      if (ra0 > M - 1) ra0 = M - 1;
    int ra1 = row0 + sr0 + 64; if (ra1 > M - 1) ra1 = M - 1;

    for (int k0 = 0; k0 < K; k0 += 32) {
        __syncthreads();
        if (AF32) {
            const float* src = &Af[(size_t)araw * K + k0 + ahalf * 16];
            float4 f0 = *(const float4*)(src + 0);
            float4 f1 = *(const float4*)(src + 4);
            float4 f2 = *(const float4*)(src + 8);
            float4 f3 = *(const float4*)(src + 12);
            uint4 lo, hi;
            lo.x = pack2(f0.x, f0.y); lo.y = pack2(f0.z, f0.w);
            lo.z = pack2(f1.x, f1.y); lo.w = pack2(f1.z, f1.w);
            hi.x = pack2(f2.x, f2.y); hi.y = pack2(f2.z, f2.w);
            hi.z = pack2(f3.x, f3.y); hi.w = pack2(f3.z, f3.w);
            *(uint4*)&As[arow * 32 + ahalf * 16 + 0] = lo;
            *(uint4*)&As[arow * 32 + ahalf * 16 + 8] = hi;
        } else {
            load_lds16(&Ab[(size_t)ra0 * K + k0 + sc], &As[(size_t)wave * 512]);
            load_lds16(&Ab[(size_t)ra1 * K + k0 + sc], &As[(size_t)(wave + 4) * 512]);
        }
#pragma unroll
        for (int g = 0; g < 4; ++g)
            load_lds16(&Bt[(size_t)(g * 64 + sr0) * K + k0 + sc],
                       &Bs[(size_t)(g * 4 + wave) * 512]);
        __syncthreads();

        bf16x8 af[4], bf[8];
#pragma unroll
        for (int mt = 0; mt < 4; ++mt)
            af[mt] = *(const bf16x8*)&As[(wm * 64 + mt * 16 + l16) * 32 + quad * 8];
#pragma unroll
        for (int nt = 0; nt < 8; ++nt)
            bf[nt] = *(const bf16x8*)&Bs[(wn * 128 + nt * 16 + l16) * 32 + quad * 8];
#pragma unroll
        for (int mt = 0; mt < 4; ++mt)
#pragma unroll
            for (int nt = 0; nt < 8; ++nt)
                acc[mt][nt] = __builtin_amdgcn_mfma_f32_16x16x32_bf16(
                    af[mt], bf[nt], acc[mt][nt], 0, 0, 0);
    }

#pragma unroll
    for (int mt = 0; mt < 4; ++mt)
#pragma unroll
        for (int r = 0; r < 4; ++r) {
            int row = row0 + wm * 64 + mt * 16 + quad * 4 + r;
            if (row < M) {
#pragma unroll
                for (int nt = 0; nt < 8; ++nt) {
                    int col = wn * 128 + nt * 16 + l16;
                    C[(size_t)row * 256 + col] = f2b(acc[mt][nt][r]);
                }
            }
        }
}

// ---------------- bf16 MFMA GEMM, 128x128 tile (m97 2-barrier) for layer 3 ----------------
template<int AF32>
__global__ __launch_bounds__(256) void gemm128(
    const void* __restrict__ Av,            // [M,K] f32 (AF32) or bf16
    const unsigned short* __restrict__ Bt,  // [Nc,K] bf16
    unsigned short* __restrict__ C,         // [M,Nc] bf16
    int M, int K, int Nc)
{
    __shared__ __align__(16) unsigned short As[128 * 32];   // 8 KB
    __shared__ __align__(16) unsigned short Bs[128 * 32];   // 8 KB
    const int t = threadIdx.x;
    const int wave = t >> 6, lane = t & 63;
    const int wm = wave & 1, wn = wave >> 1;
    const int quad = lane >> 4, l16 = lane & 15;
    const int row0 = blockIdx.y * 128, col0 = blockIdx.x * 128;

    f32x4 acc[4][4];
#pragma unroll
    for (int mt = 0; mt < 4; ++mt)
#pragma unroll
        for (int nt = 0; nt < 4; ++nt) acc[mt][nt] = (f32x4){0.f, 0.f, 0.f, 0.f};

    const int sr0 = wave * 16 + (lane >> 2);
    const int sr1 = sr0 + 64;
    const int sc  = (lane & 3) << 3;

    const float* Af = (const float*)Av;
    const unsigned short* Ab = (const unsigned short*)Av;

    const int arow = t >> 1, ahalf = t & 1;
    int araw = row0 + arow; if (araw > M - 1) araw = M - 1;

    int ra0 = row0 + sr0; if (ra0 > M - 1) ra0 = M - 1;
    int ra1 = row0 + sr1; if (ra1 > M - 1) ra1 = M - 1;
    const int rb0 = col0 + sr0;
    const int rb1 = col0 + sr1;

    for (int k0 = 0; k0 < K; k0 += 32) {
        __syncthreads();
        if (AF32) {
            const float* src = &Af[(size_t)araw * K + k0 + ahalf * 16];
            float4 f0 = *(const float4*)(src + 0);
            float4 f1 = *(const float4*)(src + 4);
            float4 f2 = *(const float4*)(src + 8);
            float4 f3 = *(const float4*)(src + 12);
            uint4 lo, hi;
            lo.x = pack2(f0.x, f0.y); lo.y = pack2(f0.z, f0.w);
            lo.z = pack2(f1.x, f1.y); lo.w = pack2(f1.z, f1.w);
            hi.x = pack2(f2.x, f2.y); hi.y = pack2(f2.z, f2.w);
            hi.z = pack2(f3.x, f3.y); hi.w = pack2(f3.z, f3.w);
            *(uint4*)&As[arow * 32 + ahalf * 16 + 0] = lo;
            *(uint4*)&As[arow * 32 + ahalf * 16 + 8] = hi;
        } else {
            load_lds16(&Ab[(size_t)ra0 * K + k0 + sc], &As[(size_t)wave * 512]);
            load_lds16(&Ab[(size_t)ra1 * K + k0 + sc], &As[(size_t)(wave + 4) * 512]);
        }
        load_lds16(&Bt[(size_t)rb0 * K + k0 + sc], &Bs[(size_t)wave * 512]);
        load_lds16(&Bt[(size_t)rb1 * K + k0 + sc], &Bs[(size_t)(wave + 4) * 512]);
        __syncthreads();

        bf16x8 af[4], bf[4];
#pragma unroll
        for (int mt = 0; mt < 4; ++mt)
            af[mt] = *(const bf16x8*)&As[(wm * 64 + mt * 16 + l16) * 32 + quad * 8];
#pragma unroll
        for (int nt = 0; nt < 4; ++nt)
            bf[nt] = *(const bf16x8*)&Bs[(wn * 64 + nt * 16 + l16) * 32 + quad * 8];
#pragma unroll
        for (int mt = 0; mt < 4; ++mt)
#pragma unroll
            for (int nt = 0; nt < 4; ++nt)
                acc[mt][nt] = __builtin_amdgcn_mfma_f32_16x16x32_bf16(
                    af[mt], bf[nt], acc[mt][nt], 0, 0, 0);
    }

#pragma unroll
    for (int mt = 0; mt < 4; ++mt)
#pragma unroll
        for (int r = 0; r < 4; ++r) {
            int row = row0 + wm * 64 + mt * 16 + quad * 4 + r;
            if (row < M) {
#pragma unroll
                for (int nt = 0; nt < 4; ++nt) {
                    int col = col0 + wn * 64 + nt * 16 + l16;
                    C[(size_t)row * Nc + col] = f2b(acc[mt][nt][r]);
                }
            }
        }
}

// ---------------- CSR SpMM, one wave per row, full 256-wide ----------------
__global__ __launch_bounds__(256) void spmm256b_kernel(const int* __restrict__ row_off,
                                                       const int2* __restrict__ ep,
                                                       const unsigned short* __restrict__ sup,
                                                       const float* __restrict__ bias,
                                                       unsigned short* __restrict__ out) {
    int row = (blockIdx.x << 2) + (threadIdx.x >> 6);
    if (row >= N_NODES) return;
    const int lane = threadIdx.x & 63;
    const int s = row_off[row], e = row_off[row + 1];
    const int cb = lane << 2;
    float a0 = 0.f, a1 = 0.f, a2 = 0.f, a3 = 0.f;

    for (int base = s; base < e; base += 64) {
        const int idx = base + lane;
        int2 p = make_int2(0, 0);            // padded lanes: col 0, val +0.0f
        if (idx < e) p = ep[idx];
        const int rem = e - base;
        const int nb = (rem < 64) ? rem : 64;
        for (int jb = 0; jb < nb; jb += 8) {
#pragma unroll
            for (int j = 0; j < 8; ++j) {
                const int col = __builtin_amdgcn_readlane(p.x, jb + j);
                const float v = __int_as_float(__builtin_amdgcn_readlane(p.y, jb + j));
                const uint2 g = *(const uint2*)&sup[((size_t)col << 8) + cb];
                a0 += v * b2f_lo(g.x); a1 += v * b2f_hi(g.x);
                a2 += v * b2f_lo(g.y); a3 += v * b2f_hi(g.y);
            }
        }
    }
    float4 bv = *(const float4*)&bias[cb];
    a0 += bv.x; a1 += bv.y; a2 += bv.z; a3 += bv.w;
    a0 = (a0 >= 0.f) ? a0 : SLOPE * a0;
    a1 = (a1 >= 0.f) ? a1 : SLOPE * a1;
    a2 = (a2 >= 0.f) ? a2 : SLOPE * a2;
    a3 = (a3 >= 0.f) ? a3 : SLOPE * a3;
    ushort4 o; o.x = f2b(a0); o.y = f2b(a1); o.z = f2b(a2); o.w = f2b(a3);
    *(ushort4*)&out[((size_t)row << 8) + cb] = o;
}

__global__ __launch_bounds__(256) void spmm128f_kernel(const int* __restrict__ row_off,
                                                       const int2* __restrict__ ep,
                                                       const unsigned short* __restrict__ sup,
                                                       const float* __restrict__ bias,
                                                       float* __restrict__ out) {
    int row = (blockIdx.x << 2) + (threadIdx.x >> 6);
    if (row >= N_NODES) return;
    const int lane = threadIdx.x & 63;
    const int s = row_off[row], e = row_off[row + 1];
    const int cb = lane << 1;
    float a0 = 0.f, a1 = 0.f;

    for (int base = s; base < e; base += 64) {
        const int idx = base + lane;
        int2 p = make_int2(0, 0);
        if (idx < e) p = ep[idx];
        const int rem = e - base;
        const int nb = (rem < 64) ? rem : 64;
        for (int jb = 0; jb < nb; jb += 8) {
#pragma unroll
            for (int j = 0; j < 8; ++j) {
                const int col = __builtin_amdgcn_readlane(p.x, jb + j);
                const float v = __int_as_float(__builtin_amdgcn_readlane(p.y, jb + j));
                const unsigned int g = *(const unsigned int*)&sup[((size_t)col << 7) + cb];
                a0 += v * b2f_lo(g); a1 += v * b2f_hi(g);
            }
        }
    }
    float2 bv = *(const float2*)&bias[cb];
    a0 += bv.x; a1 += bv.y;
    a0 = (a0 >= 0.f) ? a0 : SLOPE * a0;
    a1 = (a1 >= 0.f) ? a1 : SLOPE * a1;
    *(float2*)&out[((size_t)row << 7) + cb] = make_float2(a0, a1);
}

// ---------------- launch ----------------
extern "C" void kernel_launch(void* const* d_in, const int* in_sizes, int n_in,
                              void* d_out, int out_size, void* d_ws, size_t ws_size,
                              hipStream_t stream) {
    const float* x     = (const float*)d_in[0];
    const int*   arows = (const int*)d_in[1];
    const int*   acols = (const int*)d_in[2];
    const float* avals = (const float*)d_in[3];
    const float* W1 = (const float*)d_in[4];
    const float* b1 = (const float*)d_in[5];
    const float* W2 = (const float*)d_in[6];
    const float* b2 = (const float*)d_in[7];
    const float* W3 = (const float*)d_in[8];
    const float* b3 = (const float*)d_in[9];
    float* out = (float*)d_out;

    char* ws = (char*)d_ws;
    int2*  stagedP = (int2*)(ws);                     // 25,600,000 B
    int*   offs    = (int*) (ws + 25600000);          // 512*783*4 = 1,603,584 B
    int*   btot    = (int*) (ws + 27203584);          // 783*4 B
    int*   bbase   = (int*) (ws + 27207168);          // 783*4 B
    unsigned short* bufS = (unsigned short*)(ws + 102400000);     // 100000*256 bf16
    unsigned short* bufH = (unsigned short*)(ws + 153600000);     // 100000*256 bf16
    int2*  epack = (int2*)(ws + 204800000);                       // NNZ int2 = 25,600,000 B
    int*   roff  = (int*) (ws + 230400000);                       // N+1 i32
    unsigned short* Wt1 = (unsigned short*)(ws + 230800016);      // 262,144 B
    unsigned short* Wt2 = (unsigned short*)(ws + 231062160);      // 131,072 B
    unsigned short* Wt3 = (unsigned short*)(ws + 231193232);      // 65,536 B

    // CSR build (two-level counting sort)
    hipMemsetAsync(btot, 0, NBUCK * sizeof(int), stream);
    partition_kernel<<<PBLK, 256, 0, stream>>>(arows, acols, avals, stagedP, offs, btot);
    bscan_kernel<<<1, 1024, 0, stream>>>(btot, bbase, roff);
    place_kernel<<<NBUCK, 256, 0, stream>>>(offs, bbase, stagedP, roff, epack);

    // weight transpose (single launch, all three layers)
    wprep3_kernel<<<896, 256, 0, stream>>>(W1, Wt1, W2, Wt2, W3, Wt3);

    const int gyc = (N_NODES + 127) / 128;  // 782

    // layer 1: GEMM reads f32 x directly (conv fused into staging); A staged once
    gemm256s<1><<<gyc, 256, 0, stream>>>(x, Wt1, bufS, N_NODES, 512);
    spmm256b_kernel<<<25000, 256, 0, stream>>>(roff, epack, bufS, b1, bufH);
    // layer 2
    gemm256s<0><<<gyc, 256, 0, stream>>>(bufH, Wt2, bufS, N_NODES, 256);
    spmm256b_kernel<<<25000, 256, 0, stream>>>(roff, epack, bufS, b2, bufH);
    // layer 3
    gemm128<0><<<dim3(1, gyc), 256, 0, stream>>>(bufH, Wt3, bufS, N_NODES, 256, 128);
    spmm128f_kernel<<<25000, 256, 0, stream>>>(roff, epack, bufS, b3, out);
}

// Round 8
// 1101.915 us; speedup vs baseline: 1.0528x; 1.0528x over previous
//
#include <hip/hip_runtime.h>

#define N_NODES 100000
#define NNZ_E   3200000
#define SLOPE   0.25f

// ---- bucket sort geometry ----
#define NBUCK 782      // ceil(100000/128); bucket = row >> 7 (128 rows/bucket)
#define PBLK  512      // partition blocks
#define PCH   6250     // edges per partition block (512*6250 = 3,200,000 exact)

typedef __attribute__((ext_vector_type(8))) short bf16x8;
typedef __attribute__((ext_vector_type(4))) float f32x4;

// f32 -> bf16 round-to-nearest-even (bit trick)
__device__ __forceinline__ unsigned short f2b(float f) {
    union { float f; unsigned int u; } c; c.f = f;
    unsigned int u = c.u + 0x7fffu + ((c.u >> 16) & 1u);
    return (unsigned short)(u >> 16);
}
__device__ __forceinline__ unsigned int pack2(float a, float b) {
    return (unsigned int)f2b(a) | ((unsigned int)f2b(b) << 16);
}
__device__ __forceinline__ float b2f_lo(unsigned int u) {
    union { unsigned int u; float f; } c; c.u = u << 16; return c.f;
}
__device__ __forceinline__ float b2f_hi(unsigned int u) {
    union { unsigned int u; float f; } c; c.u = u & 0xffff0000u; return c.f;
}

// async global->LDS, 16B per lane; LDS dest is wave-uniform base + lane*16
__device__ __forceinline__ void load_lds16(const unsigned short* gp, unsigned short* lp) {
    __builtin_amdgcn_global_load_lds(
        (const __attribute__((address_space(1))) void*)gp,
        (__attribute__((address_space(3))) void*)lp, 16, 0, 0);
}

// ---------------- CSR build: two-level counting sort ----------------
__global__ __launch_bounds__(256) void partition_kernel(
    const int* __restrict__ rows, const int* __restrict__ cols,
    const float* __restrict__ vals,
    int2* __restrict__ stagedP,
    int* __restrict__ offs /*[PBLK][NBUCK+1]*/, int* __restrict__ btot)
{
    __shared__ int hist[NBUCK];   // counts, then running cursors
    __shared__ int ts[256];
    const int blk = blockIdx.x, t = threadIdx.x;
    const int base = blk * PCH;

    for (int i = t; i < NBUCK; i += 256) hist[i] = 0;
    __syncthreads();
    for (int e = t; e < PCH; e += 256)
        atomicAdd(&hist[rows[base + e] >> 7], 1);
    __syncthreads();

    // exclusive scan over 782 buckets: 4 entries per thread + 256-thread scan
    const int i0 = t << 2;
    int c0 = (i0 + 0 < NBUCK) ? hist[i0 + 0] : 0;
    int c1 = (i0 + 1 < NBUCK) ? hist[i0 + 1] : 0;
    int c2 = (i0 + 2 < NBUCK) ? hist[i0 + 2] : 0;
    int c3 = (i0 + 3 < NBUCK) ? hist[i0 + 3] : 0;
    int s = c0 + c1 + c2 + c3;
    ts[t] = s; __syncthreads();
    for (int off = 1; off < 256; off <<= 1) {
        int u = (t >= off) ? ts[t - off] : 0;
        __syncthreads();
        ts[t] += u;
        __syncthreads();
    }
    int ex = ts[t] - s;
    int o0 = ex, o1 = ex + c0, o2 = o1 + c1, o3 = o2 + c2;
    int* gof = offs + blk * (NBUCK + 1);
    if (i0 + 0 < NBUCK) { hist[i0 + 0] = o0; gof[i0 + 0] = o0; if (c0) atomicAdd(&btot[i0 + 0], c0); }
    if (i0 + 1 < NBUCK) { hist[i0 + 1] = o1; gof[i0 + 1] = o1; if (c1) atomicAdd(&btot[i0 + 1], c1); }
    if (i0 + 2 < NBUCK) { hist[i0 + 2] = o2; gof[i0 + 2] = o2; if (c2) atomicAdd(&btot[i0 + 2], c2); }
    if (i0 + 3 < NBUCK) { hist[i0 + 3] = o3; gof[i0 + 3] = o3; if (c3) atomicAdd(&btot[i0 + 3], c3); }
    if (t == 255) gof[NBUCK] = ts[255];   // == PCH
    __syncthreads();

    // scatter into block-local staged region (random only within ~50 KB, L2-held)
    for (int e = t; e < PCH; e += 256) {
        int r = rows[base + e];
        int p = atomicAdd(&hist[r >> 7], 1);
        stagedP[base + p] = make_int2(((r & 127) << 17) | cols[base + e],
                                      __float_as_int(vals[base + e]));
    }
}

// Pass 1b: exclusive scan of bucket totals -> epack base per bucket
__global__ __launch_bounds__(1024) void bscan_kernel(const int* __restrict__ btot,
                                                     int* __restrict__ bbase,
                                                     int* __restrict__ roff) {
    __shared__ int lds[1024];
    int t = threadIdx.x;
    int v = (t < NBUCK) ? btot[t] : 0;
    lds[t] = v; __syncthreads();
    for (int off = 1; off < 1024; off <<= 1) {
        int u = (t >= off) ? lds[t - off] : 0;
        __syncthreads();
        lds[t] += u;
        __syncthreads();
    }
    if (t < NBUCK) bbase[t] = lds[t] - v;
    if (t == 0) { bbase[NBUCK] = NNZ_E; roff[N_NODES] = NNZ_E; }
}

// Pass 2: one block per bucket. Two direct passes over the bucket's 512 slices:
// count rows -> scan -> place via per-row cursors. LDS ~6 KB -> high occupancy.
__global__ __launch_bounds__(256) void place_kernel(
    const int* __restrict__ offs, const int* __restrict__ bbase,
    const int2* __restrict__ stagedP,
    int* __restrict__ roff, int2* __restrict__ epack)
{
    __shared__ int sstart[PBLK];
    __shared__ int slen[PBLK];
    __shared__ int cnt[128];
    __shared__ int rex[128];
    const int b = blockIdx.x, t = threadIdx.x;

    for (int i = t; i < PBLK; i += 256) {
        int s = offs[i * (NBUCK + 1) + b];
        int e = offs[i * (NBUCK + 1) + b + 1];
        sstart[i] = s;
        slen[i] = e - s;
    }
    if (t < 128) cnt[t] = 0;
    __syncthreads();

    // count pass: row histogram (read only .x of each staged edge)
    for (int i = t; i < PBLK; i += 256) {
        const int s0 = sstart[i], len = slen[i];
        const int* p = (const int*)(stagedP + (size_t)i * PCH + s0);
        for (int j = 0; j < len; ++j) {
            int rl = (p[2 * j] >> 17) & 127;
            atomicAdd(&cnt[rl], 1);
        }
    }
    __syncthreads();

    // exclusive scan of 128 row counts
    int cv = (t < 128) ? cnt[t] : 0;
    if (t < 128) rex[t] = cv;
    __syncthreads();
    for (int off = 1; off < 128; off <<= 1) {
        int u = (t >= off && t < 128) ? rex[t - off] : 0;
        __syncthreads();
        if (t < 128) rex[t] += u;
        __syncthreads();
    }
    const int bb = bbase[b];
    int exl = (t < 128) ? (rex[t] - cv) : 0;
    __syncthreads();
    if (t < 128) {
        rex[t] = exl;
        cnt[t] = 0;                   // becomes per-row cursor
        int idx = (b << 7) + t;
        if (idx < N_NODES) roff[idx] = bb + exl;
    }
    __syncthreads();

    // place pass
    for (int i = t; i < PBLK; i += 256) {
        const int s0 = sstart[i], len = slen[i];
        const int2* p = stagedP + (size_t)i * PCH + s0;
        for (int j = 0; j < len; ++j) {
            int2 ed = p[j];
            int rl = (ed.x >> 17) & 127;
            int pos = bb + rex[rl] + atomicAdd(&cnt[rl], 1);
            epack[pos] = make_int2(ed.x & 0x1FFFF, ed.y);
        }
    }
}

// ---------------- weight prep (all three layers in one launch) ----------------
__global__ __launch_bounds__(256) void wprep3_kernel(
    const float* __restrict__ W1, unsigned short* __restrict__ Wt1,
    const float* __restrict__ W2, unsigned short* __restrict__ Wt2,
    const float* __restrict__ W3, unsigned short* __restrict__ Wt3)
{
    int idx = blockIdx.x * blockDim.x + threadIdx.x;
    if (idx < 131072) {                    // W1: 512x256
        int n = idx >> 9, k = idx & 511;
        Wt1[idx] = f2b(W1[(size_t)k * 256 + n]);
    } else if (idx < 131072 + 65536) {     // W2: 256x256
        int i = idx - 131072;
        int n = i >> 8, k = i & 255;
        Wt2[i] = f2b(W2[(size_t)k * 256 + n]);
    } else if (idx < 131072 + 65536 + 32768) {  // W3: 256x128
        int i = idx - 131072 - 65536;
        int n = i >> 8, k = i & 255;
        Wt3[i] = f2b(W3[(size_t)k * 128 + n]);
    }
}

// ---------------- bf16 MFMA GEMM, 128x128 tile (m97 2-barrier structure) ----------------
// Single 16 KB LDS buffer, 64-VGPR accumulator -> 4+ blocks/CU residency.
// AF32=1: A is f32, converted to bf16 in-register during staging (fuses conv).
template<int AF32>
__global__ __launch_bounds__(256) void gemm128(
    const void* __restrict__ Av,            // [M,K] f32 (AF32) or bf16
    const unsigned short* __restrict__ Bt,  // [Nc,K] bf16
    unsigned short* __restrict__ C,         // [M,Nc] bf16
    int M, int K, int Nc)
{
    __shared__ __align__(16) unsigned short As[128 * 32];   // 8 KB
    __shared__ __align__(16) unsigned short Bs[128 * 32];   // 8 KB
    const int t = threadIdx.x;
    const int wave = t >> 6, lane = t & 63;
    const int wm = wave & 1, wn = wave >> 1;
    const int quad = lane >> 4, l16 = lane & 15;
    const int row0 = blockIdx.y * 128, col0 = blockIdx.x * 128;

    f32x4 acc[4][4];
#pragma unroll
    for (int mt = 0; mt < 4; ++mt)
#pragma unroll
        for (int nt = 0; nt < 4; ++nt) acc[mt][nt] = (f32x4){0.f, 0.f, 0.f, 0.f};

    const int sr0 = wave * 16 + (lane >> 2);
    const int sr1 = sr0 + 64;
    const int sc  = (lane & 3) << 3;

    const float* Af = (const float*)Av;
    const unsigned short* Ab = (const unsigned short*)Av;

    // AF32 staging map: thread t -> row t>>1, 16-col half t&1
    const int arow = t >> 1, ahalf = t & 1;
    int araw = row0 + arow; if (araw > M - 1) araw = M - 1;

    int ra0 = row0 + sr0; if (ra0 > M - 1) ra0 = M - 1;
    int ra1 = row0 + sr1; if (ra1 > M - 1) ra1 = M - 1;
    const int rb0 = col0 + sr0;
    const int rb1 = col0 + sr1;

    for (int k0 = 0; k0 < K; k0 += 32) {
        __syncthreads();
        if (AF32) {
            const float* src = &Af[(size_t)araw * K + k0 + ahalf * 16];
            float4 f0 = *(const float4*)(src + 0);
            float4 f1 = *(const float4*)(src + 4);
            float4 f2 = *(const float4*)(src + 8);
            float4 f3 = *(const float4*)(src + 12);
            uint4 lo, hi;
            lo.x = pack2(f0.x, f0.y); lo.y = pack2(f0.z, f0.w);
            lo.z = pack2(f1.x, f1.y); lo.w = pack2(f1.z, f1.w);
            hi.x = pack2(f2.x, f2.y); hi.y = pack2(f2.z, f2.w);
            hi.z = pack2(f3.x, f3.y); hi.w = pack2(f3.z, f3.w);
            *(uint4*)&As[arow * 32 + ahalf * 16 + 0] = lo;
            *(uint4*)&As[arow * 32 + ahalf * 16 + 8] = hi;
        } else {
            load_lds16(&Ab[(size_t)ra0 * K + k0 + sc], &As[(size_t)wave * 512]);
            load_lds16(&Ab[(size_t)ra1 * K + k0 + sc], &As[(size_t)(wave + 4) * 512]);
        }
        load_lds16(&Bt[(size_t)rb0 * K + k0 + sc], &Bs[(size_t)wave * 512]);
        load_lds16(&Bt[(size_t)rb1 * K + k0 + sc], &Bs[(size_t)(wave + 4) * 512]);
        __syncthreads();

        bf16x8 af[4], bf[4];
#pragma unroll
        for (int mt = 0; mt < 4; ++mt)
            af[mt] = *(const bf16x8*)&As[(wm * 64 + mt * 16 + l16) * 32 + quad * 8];
#pragma unroll
        for (int nt = 0; nt < 4; ++nt)
            bf[nt] = *(const bf16x8*)&Bs[(wn * 64 + nt * 16 + l16) * 32 + quad * 8];
#pragma unroll
        for (int mt = 0; mt < 4; ++mt)
#pragma unroll
            for (int nt = 0; nt < 4; ++nt)
                acc[mt][nt] = __builtin_amdgcn_mfma_f32_16x16x32_bf16(
                    af[mt], bf[nt], acc[mt][nt], 0, 0, 0);
    }

#pragma unroll
    for (int mt = 0; mt < 4; ++mt)
#pragma unroll
        for (int r = 0; r < 4; ++r) {
            int row = row0 + wm * 64 + mt * 16 + quad * 4 + r;
            if (row < M) {
#pragma unroll
                for (int nt = 0; nt < 4; ++nt) {
                    int col = col0 + wn * 64 + nt * 16 + l16;
                    C[(size_t)row * Nc + col] = f2b(acc[mt][nt][r]);
                }
            }
        }
}

// ---------------- CSR SpMM, one wave per row, FEATURE-HALF pass ----------------
__global__ __launch_bounds__(256) void spmm256h_kernel(const int* __restrict__ row_off,
                                                       const int2* __restrict__ ep,
                                                       const unsigned short* __restrict__ sup,
                                                       const float* __restrict__ bias,
                                                       unsigned short* __restrict__ out,
                                                       int half) {
    int row = (blockIdx.x << 2) + (threadIdx.x >> 6);
    if (row >= N_NODES) return;
    const int lane = threadIdx.x & 63;
    const int s = row_off[row], e = row_off[row + 1];
    const int cb = (half << 7) + (lane << 1);    // 2 cols per lane within the half
    float a0 = 0.f, a1 = 0.f;

    for (int base = s; base < e; base += 64) {
        const int idx = base + lane;
        int2 p = make_int2(0, 0);            // padded lanes: col 0, val +0.0f
        if (idx < e) p = ep[idx];
        const int rem = e - base;
        const int nb = (rem < 64) ? rem : 64;
        for (int jb = 0; jb < nb; jb += 8) {
#pragma unroll
            for (int j = 0; j < 8; ++j) {
                const int col = __builtin_amdgcn_readlane(p.x, jb + j);
                const float v = __int_as_float(__builtin_amdgcn_readlane(p.y, jb + j));
                const unsigned int g = *(const unsigned int*)&sup[((size_t)col << 8) + cb];
                a0 += v * b2f_lo(g); a1 += v * b2f_hi(g);
            }
        }
    }
    float2 bv = *(const float2*)&bias[cb];
    a0 += bv.x; a1 += bv.y;
    a0 = (a0 >= 0.f) ? a0 : SLOPE * a0;
    a1 = (a1 >= 0.f) ? a1 : SLOPE * a1;
    ushort2 o; o.x = f2b(a0); o.y = f2b(a1);
    *(ushort2*)&out[((size_t)row << 8) + cb] = o;
}

__global__ __launch_bounds__(256) void spmm128f_kernel(const int* __restrict__ row_off,
                                                       const int2* __restrict__ ep,
                                                       const unsigned short* __restrict__ sup,
                                                       const float* __restrict__ bias,
                                                       float* __restrict__ out) {
    int row = (blockIdx.x << 2) + (threadIdx.x >> 6);
    if (row >= N_NODES) return;
    const int lane = threadIdx.x & 63;
    const int s = row_off[row], e = row_off[row + 1];
    const int cb = lane << 1;
    float a0 = 0.f, a1 = 0.f;

    for (int base = s; base < e; base += 64) {
        const int idx = base + lane;
        int2 p = make_int2(0, 0);
        if (idx < e) p = ep[idx];
        const int rem = e - base;
        const int nb = (rem < 64) ? rem : 64;
        for (int jb = 0; jb < nb; jb += 8) {
#pragma unroll
            for (int j = 0; j < 8; ++j) {
                const int col = __builtin_amdgcn_readlane(p.x, jb + j);
                const float v = __int_as_float(__builtin_amdgcn_readlane(p.y, jb + j));
                const unsigned int g = *(const unsigned int*)&sup[((size_t)col << 7) + cb];
                a0 += v * b2f_lo(g); a1 += v * b2f_hi(g);
            }
        }
    }
    float2 bv = *(const float2*)&bias[cb];
    a0 += bv.x; a1 += bv.y;
    a0 = (a0 >= 0.f) ? a0 : SLOPE * a0;
    a1 = (a1 >= 0.f) ? a1 : SLOPE * a1;
    *(float2*)&out[((size_t)row << 7) + cb] = make_float2(a0, a1);
}

// ---------------- launch ----------------
extern "C" void kernel_launch(void* const* d_in, const int* in_sizes, int n_in,
                              void* d_out, int out_size, void* d_ws, size_t ws_size,
                              hipStream_t stream) {
    const float* x     = (const float*)d_in[0];
    const int*   arows = (const int*)d_in[1];
    const int*   acols = (const int*)d_in[2];
    const float* avals = (const float*)d_in[3];
    const float* W1 = (const float*)d_in[4];
    const float* b1 = (const float*)d_in[5];
    const float* W2 = (const float*)d_in[6];
    const float* b2 = (const float*)d_in[7];
    const float* W3 = (const float*)d_in[8];
    const float* b3 = (const float*)d_in[9];
    float* out = (float*)d_out;

    char* ws = (char*)d_ws;
    int2*  stagedP = (int2*)(ws);                     // 25,600,000 B
    int*   offs    = (int*) (ws + 25600000);          // 512*783*4 = 1,603,584 B
    int*   btot    = (int*) (ws + 27203584);          // 783*4 B
    int*   bbase   = (int*) (ws + 27207168);          // 783*4 B
    unsigned short* bufS = (unsigned short*)(ws + 102400000);     // 100000*256 bf16
    unsigned short* bufH = (unsigned short*)(ws + 153600000);     // 100000*256 bf16
    int2*  epack = (int2*)(ws + 204800000);                       // NNZ int2 = 25,600,000 B
    int*   roff  = (int*) (ws + 230400000);                       // N+1 i32
    unsigned short* Wt1 = (unsigned short*)(ws + 230800016);      // 262,144 B
    unsigned short* Wt2 = (unsigned short*)(ws + 231062160);      // 131,072 B
    unsigned short* Wt3 = (unsigned short*)(ws + 231193232);      // 65,536 B

    // CSR build (two-level counting sort)
    hipMemsetAsync(btot, 0, NBUCK * sizeof(int), stream);
    partition_kernel<<<PBLK, 256, 0, stream>>>(arows, acols, avals, stagedP, offs, btot);
    bscan_kernel<<<1, 1024, 0, stream>>>(btot, bbase, roff);
    place_kernel<<<NBUCK, 256, 0, stream>>>(offs, bbase, stagedP, roff, epack);

    // weight transpose (single launch, all three layers)
    wprep3_kernel<<<896, 256, 0, stream>>>(W1, Wt1, W2, Wt2, W3, Wt3);

    const int gyc = (N_NODES + 127) / 128;  // 782

    // layer 1: GEMM reads f32 x directly (conv fused into staging)
    gemm128<1><<<dim3(2, gyc), 256, 0, stream>>>(x, Wt1, bufS, N_NODES, 512, 256);
    spmm256h_kernel<<<25000, 256, 0, stream>>>(roff, epack, bufS, b1, bufH, 0);
    spmm256h_kernel<<<25000, 256, 0, stream>>>(roff, epack, bufS, b1, bufH, 1);
    // layer 2
    gemm128<0><<<dim3(2, gyc), 256, 0, stream>>>(bufH, Wt2, bufS, N_NODES, 256, 256);
    spmm256h_kernel<<<25000, 256, 0, stream>>>(roff, epack, bufS, b2, bufH, 0);
    spmm256h_kernel<<<25000, 256, 0, stream>>>(roff, epack, bufS, b2, bufH, 1);
    // layer 3
    gemm128<0><<<dim3(1, gyc), 256, 0, stream>>>(bufH, Wt3, bufS, N_NODES, 256, 128);
    spmm128f_kernel<<<25000, 256, 0, stream>>>(roff, epack, bufS, b3, out);
}